// Round 9
// baseline (91.855 us; speedup 1.0000x reference)
//
#include <hip/hip_runtime.h>

// LocallyConnected3D: out[b,l,f] = sum_p patch[b,l,p] * W[l,p,f] + bias[l,f]
// W = (27000,216,16) f32 = 373 MB streamed once -> HBM-bound.
// One wave per location, barrier-free (single-wave block, wave-private LDS).
// R9 = R8 minus nontemporal (nt regressed 74->90us; isolate width variable):
// weight stream as 14 x float4 (16B/lane, 1KB/wave-instr), plain cached
// loads/stores. Lane = p_res*4 + fq; butterfly reduce over 16 p-residues.

#define LLOC 27000
#define PDIM 216
#define FDIM 16
#define CIN 8

typedef float f32x4 __attribute__((ext_vector_type(4)));

__global__ __launch_bounds__(64) void lc3d_kernel(
    const float* __restrict__ x,
    const float* __restrict__ w,
    const float* __restrict__ bias,
    float* __restrict__ out)
{
    const int l = blockIdx.x;
    const int lane = threadIdx.x;       // 0..63
    const int od = l / 900;
    const int rl = l - od * 900;
    const int oh = rl / 30;
    const int ow = rl - oh * 30;

    __shared__ float patch[4 * PDIM];   // [b][p], p = (kd*9+kh*3+kw)*8 + c

    // ---- Phase 1a: issue x gather loads into registers ----
    float4 xv[4];
    int ldst[4];
    #pragma unroll
    for (int i = 0; i < 4; ++i) {
        const int idx   = i * 64 + lane;        // 0..255, 216 real chunks
        const bool vld  = idx < 216;
        const int cidx  = vld ? idx : 0;
        const int b     = cidx / 54;            // 54 float4 per batch
        const int r     = cidx - b * 54;
        const int slab  = r >> 1;               // kd*9 + kh*3 + kw
        const int half  = r & 1;
        const int kd    = slab / 9;
        const int r2    = slab - kd * 9;
        const int kh    = r2 / 3;
        const int kw    = r2 - kh * 3;
        ldst[i] = vld ? (b * PDIM + slab * 8 + half * 4) : -1;
        xv[i] = *reinterpret_cast<const float4*>(
            x + ((((b * 32 + od + kd) * 32 + (oh + kh)) * 32 + (ow + kw)) * CIN
                 + half * 4));
    }

    // ---- Phase 1b: weight stream, 14 x float4 (1KB/wave), cached ----
    // idx4 = i*64+lane: p = idx4>>2, f quad = idx4&3.
    const f32x4* wb4 =
        reinterpret_cast<const f32x4*>(w + (size_t)l * (PDIM * FDIM));
    f32x4 wr[14];
    #pragma unroll
    for (int i = 0; i < 14; ++i) {
        const int idx4 = i * 64 + lane;          // < 864 except tail of i=13
        const int cl   = idx4 < 864 ? idx4 : 863;
        wr[i] = wb4[cl];
    }

    // ---- Phase 1c: write patch to LDS (waits only on the older x loads;
    //      weight loads remain outstanding in the vmcnt FIFO) ----
    #pragma unroll
    for (int i = 0; i < 4; ++i)
        if (ldst[i] >= 0)
            *reinterpret_cast<float4*>(&patch[ldst[i]]) = xv[i];

    // ---- Phase 2: FMA; progressive vmcnt per wr[i] ----
    const int pres = lane >> 2;                 // p residue mod 16 (0..15)

    f32x4 acc[4] = {};                          // [b], 4 f's each
    #pragma unroll
    for (int i = 0; i < 14; ++i) {
        int p = i * 16 + pres;
        f32x4 wv = wr[i];
        if (i == 13) {                          // tail: only lanes<32 valid
            const bool valid = (p < PDIM);
            wv = valid ? wv : (f32x4)0.0f;
            p  = valid ? p : 0;
        }
        #pragma unroll
        for (int b = 0; b < 4; ++b) {
            const float pv = patch[b * PDIM + p];   // LDS broadcast (4 lanes/addr)
            acc[b].x = fmaf(pv, wv.x, acc[b].x);
            acc[b].y = fmaf(pv, wv.y, acc[b].y);
            acc[b].z = fmaf(pv, wv.z, acc[b].z);
            acc[b].w = fmaf(pv, wv.w, acc[b].w);
        }
    }

    // ---- Phase 3: butterfly reduce across 16 p-residue groups
    //      (masks 4/8/16/32 flip pres bits; totals replicate to all lanes) ----
    #pragma unroll
    for (int b = 0; b < 4; ++b) {
        #pragma unroll
        for (int m = 4; m <= 32; m <<= 1) {
            acc[b].x += __shfl_xor(acc[b].x, m, 64);
            acc[b].y += __shfl_xor(acc[b].y, m, 64);
            acc[b].z += __shfl_xor(acc[b].z, m, 64);
            acc[b].w += __shfl_xor(acc[b].w, m, 64);
        }
    }

    // ---- Epilogue: lanes 0..15 store all 4 batches in ONE instruction:
    //      lane = b*4 + q, each lane stores 16B (f = q*4..q*4+3) ----
    if (lane < 16) {
        const int b = lane >> 2;
        const int q = lane & 3;
        const float4 bv =
            *reinterpret_cast<const float4*>(bias + l * FDIM + q * 4);
        f32x4 v = acc[0];
        if (b == 1) v = acc[1];
        if (b == 2) v = acc[2];
        if (b == 3) v = acc[3];
        f32x4 o;
        o.x = v.x + bv.x;
        o.y = v.y + bv.y;
        o.z = v.z + bv.z;
        o.w = v.w + bv.w;
        *reinterpret_cast<f32x4*>(
            out + ((size_t)b * LLOC + l) * FDIM + q * 4) = o;
    }
}

extern "C" void kernel_launch(void* const* d_in, const int* in_sizes, int n_in,
                              void* d_out, int out_size, void* d_ws, size_t ws_size,
                              hipStream_t stream) {
    const float* x    = (const float*)d_in[0];
    const float* wgt  = (const float*)d_in[1];
    const float* bias = (const float*)d_in[2];
    float* out        = (float*)d_out;

    lc3d_kernel<<<dim3(LLOC), dim3(64), 0, stream>>>(x, wgt, bias, out);
}

// Round 10
// 72.134 us; speedup vs baseline: 1.2734x; 1.2734x over previous
//
#include <hip/hip_runtime.h>

// LocallyConnected3D: out[b,l,f] = sum_p patch[b,l,p] * W[l,p,f] + bias[l,f]
// W = (27000,216,16) f32 = 373 MB streamed once -> HBM-bound.
// One wave per location, barrier-free (single-wave block, wave-private LDS).
// R10 = R6 (measured best, 74.2us) + ONE change: weight loads marked
// nontemporal (evict-first) so the 373MB single-use stream doesn't flush
// x (4MB) out of L2/L3 — x gather re-fetches were ~93MB of extra HBM traffic
// if uncached. Everything else byte-identical to R6.

#define LLOC 27000
#define PDIM 216
#define FDIM 16
#define CIN 8

typedef float f32x2 __attribute__((ext_vector_type(2)));

__global__ __launch_bounds__(64) void lc3d_kernel(
    const float* __restrict__ x,
    const float* __restrict__ w,
    const float* __restrict__ bias,
    float* __restrict__ out)
{
    const int l = blockIdx.x;
    const int lane = threadIdx.x;       // 0..63
    const int od = l / 900;
    const int rl = l - od * 900;
    const int oh = rl / 30;
    const int ow = rl - oh * 30;

    __shared__ float patch[4 * PDIM];   // [b][p], p = (kd*9+kh*3+kw)*8 + c

    // ---- Phase 1a: issue x gather loads into registers ----
    float4 xv[4];
    int ldst[4];
    #pragma unroll
    for (int i = 0; i < 4; ++i) {
        const int idx   = i * 64 + lane;        // 0..255, 216 real chunks
        const bool vld  = idx < 216;
        const int cidx  = vld ? idx : 0;
        const int b     = cidx / 54;            // 54 float4 per batch
        const int r     = cidx - b * 54;
        const int slab  = r >> 1;               // kd*9 + kh*3 + kw
        const int half  = r & 1;
        const int kd    = slab / 9;
        const int r2    = slab - kd * 9;
        const int kh    = r2 / 3;
        const int kw    = r2 - kh * 3;
        ldst[i] = vld ? (b * PDIM + slab * 8 + half * 4) : -1;
        xv[i] = *reinterpret_cast<const float4*>(
            x + ((((b * 32 + od + kd) * 32 + (oh + kh)) * 32 + (ow + kw)) * CIN
                 + half * 4));
    }

    // ---- Phase 1b: weight stream (27 x 512B/wave), NONTEMPORAL ----
    const int pidx = lane >> 3;                 // p % 8   (== input channel c)
    const int fh   = lane & 7;                  // f pair index
    const f32x2* wbase =
        reinterpret_cast<const f32x2*>(w + (size_t)l * (PDIM * FDIM));
    f32x2 wr[27];
    #pragma unroll
    for (int i = 0; i < 27; ++i)
        wr[i] = __builtin_nontemporal_load(wbase + i * 64 + lane);

    // ---- Phase 1c: write patch to LDS (waits only on the older x loads;
    //      weight loads remain outstanding in the vmcnt FIFO) ----
    #pragma unroll
    for (int i = 0; i < 4; ++i)
        if (ldst[i] >= 0)
            *reinterpret_cast<float4*>(&patch[ldst[i]]) = xv[i];

    // ---- Phase 2: FMA; progressive vmcnt per wr[i] ----
    float acc[4][2] = {};
    #pragma unroll
    for (int i = 0; i < 27; ++i) {
        const int p = i * 8 + pidx;
        #pragma unroll
        for (int b = 0; b < 4; ++b) {
            const float pv = patch[b * PDIM + p];   // LDS broadcast, conflict-free
            acc[b][0] = fmaf(pv, wr[i].x, acc[b][0]);
            acc[b][1] = fmaf(pv, wr[i].y, acc[b][1]);
        }
    }

    // ---- Phase 3: reduce across the 8 pidx groups ----
    #pragma unroll
    for (int b = 0; b < 4; ++b) {
        #pragma unroll
        for (int j = 0; j < 2; ++j) {
            float v = acc[b][j];
            v += __shfl_xor(v, 8, 64);
            v += __shfl_xor(v, 16, 64);
            v += __shfl_xor(v, 32, 64);
            acc[b][j] = v;
        }
    }

    // ---- Epilogue: lanes 0..7 hold full sums; write all 4 batches ----
    if (pidx == 0) {
        const float2 bv =
            *reinterpret_cast<const float2*>(bias + l * FDIM + fh * 2);
        #pragma unroll
        for (int b = 0; b < 4; ++b) {
            float2 o;
            o.x = acc[b][0] + bv.x;
            o.y = acc[b][1] + bv.y;
            *reinterpret_cast<float2*>(
                out + ((size_t)b * LLOC + l) * FDIM + fh * 2) = o;
        }
    }
}

extern "C" void kernel_launch(void* const* d_in, const int* in_sizes, int n_in,
                              void* d_out, int out_size, void* d_ws, size_t ws_size,
                              hipStream_t stream) {
    const float* x    = (const float*)d_in[0];
    const float* wgt  = (const float*)d_in[1];
    const float* bias = (const float*)d_in[2];
    float* out        = (float*)d_out;

    lc3d_kernel<<<dim3(LLOC), dim3(64), 0, stream>>>(x, wgt, bias, out);
}

// Round 11
// 66.817 us; speedup vs baseline: 1.3747x; 1.0796x over previous
//
#include <hip/hip_runtime.h>

// LocallyConnected3D: out[b,l,f] = sum_p patch[b,l,p] * W[l,p,f] + bias[l,f]
// W = (27000,216,16) f32 = 373 MB streamed once -> HBM-bound.
// R11 = R10 + dispatch amortization: 4 independent waves per block (256 thr),
// each wave owns one location l = blockIdx*4 + waveId; grid 27000 -> 6750.
// Still barrier-free (per-wave LDS regions). Weight stream nontemporal.

#define LLOC 27000
#define PDIM 216
#define FDIM 16
#define CIN 8

typedef float f32x2 __attribute__((ext_vector_type(2)));

__global__ __launch_bounds__(256) void lc3d_kernel(
    const float* __restrict__ x,
    const float* __restrict__ w,
    const float* __restrict__ bias,
    float* __restrict__ out)
{
    const int wid  = threadIdx.x >> 6;  // wave 0..3
    const int lane = threadIdx.x & 63;
    const int l = blockIdx.x * 4 + wid;
    const int od = l / 900;
    const int rl = l - od * 900;
    const int oh = rl / 30;
    const int ow = rl - oh * 30;

    __shared__ float patch[4][4 * PDIM];   // [wave][b*PDIM + p]
    float* mypatch = patch[wid];

    // ---- Phase 1a: issue x gather loads into registers ----
    float4 xv[4];
    int ldst[4];
    #pragma unroll
    for (int i = 0; i < 4; ++i) {
        const int idx   = i * 64 + lane;        // 0..255, 216 real chunks
        const bool vld  = idx < 216;
        const int cidx  = vld ? idx : 0;
        const int b     = cidx / 54;            // 54 float4 per batch
        const int r     = cidx - b * 54;
        const int slab  = r >> 1;               // kd*9 + kh*3 + kw
        const int half  = r & 1;
        const int kd    = slab / 9;
        const int r2    = slab - kd * 9;
        const int kh    = r2 / 3;
        const int kw    = r2 - kh * 3;
        ldst[i] = vld ? (b * PDIM + slab * 8 + half * 4) : -1;
        xv[i] = *reinterpret_cast<const float4*>(
            x + ((((b * 32 + od + kd) * 32 + (oh + kh)) * 32 + (ow + kw)) * CIN
                 + half * 4));
    }

    // ---- Phase 1b: weight stream (27 x 512B/wave), nontemporal ----
    const int pidx = lane >> 3;                 // p % 8   (== input channel c)
    const int fh   = lane & 7;                  // f pair index
    const f32x2* wbase =
        reinterpret_cast<const f32x2*>(w + (size_t)l * (PDIM * FDIM));
    f32x2 wr[27];
    #pragma unroll
    for (int i = 0; i < 27; ++i)
        wr[i] = __builtin_nontemporal_load(wbase + i * 64 + lane);

    // ---- Phase 1c: write patch to LDS (waits only on the older x loads;
    //      weight loads remain outstanding in the vmcnt FIFO) ----
    #pragma unroll
    for (int i = 0; i < 4; ++i)
        if (ldst[i] >= 0)
            *reinterpret_cast<float4*>(&mypatch[ldst[i]]) = xv[i];

    // ---- Phase 2: FMA; progressive vmcnt per wr[i] ----
    float acc[4][2] = {};
    #pragma unroll
    for (int i = 0; i < 27; ++i) {
        const int p = i * 8 + pidx;
        #pragma unroll
        for (int b = 0; b < 4; ++b) {
            const float pv = mypatch[b * PDIM + p];   // LDS broadcast, conflict-free
            acc[b][0] = fmaf(pv, wr[i].x, acc[b][0]);
            acc[b][1] = fmaf(pv, wr[i].y, acc[b][1]);
        }
    }

    // ---- Phase 3: reduce across the 8 pidx groups ----
    #pragma unroll
    for (int b = 0; b < 4; ++b) {
        #pragma unroll
        for (int j = 0; j < 2; ++j) {
            float v = acc[b][j];
            v += __shfl_xor(v, 8, 64);
            v += __shfl_xor(v, 16, 64);
            v += __shfl_xor(v, 32, 64);
            acc[b][j] = v;
        }
    }

    // ---- Epilogue: lanes 0..7 hold full sums; write all 4 batches ----
    if (pidx == 0) {
        const float2 bv =
            *reinterpret_cast<const float2*>(bias + l * FDIM + fh * 2);
        #pragma unroll
        for (int b = 0; b < 4; ++b) {
            float2 o;
            o.x = acc[b][0] + bv.x;
            o.y = acc[b][1] + bv.y;
            *reinterpret_cast<float2*>(
                out + ((size_t)b * LLOC + l) * FDIM + fh * 2) = o;
        }
    }
}

extern "C" void kernel_launch(void* const* d_in, const int* in_sizes, int n_in,
                              void* d_out, int out_size, void* d_ws, size_t ws_size,
                              hipStream_t stream) {
    const float* x    = (const float*)d_in[0];
    const float* wgt  = (const float*)d_in[1];
    const float* bias = (const float*)d_in[2];
    float* out        = (float*)d_out;

    lc3d_kernel<<<dim3(LLOC / 4), dim3(256), 0, stream>>>(x, wgt, bias, out);
}